// Round 3
// baseline (266.426 us; speedup 1.0000x reference)
//
#include <hip/hip_runtime.h>

// Embedding gather: out[token, :] = kernel[idx[token], :]  (all f32)
// TOKENS = 262144, EMBED = 256 (1 KiB/row), VOCAB = 256 (table 256 KiB).
// Output = 256 MiB HBM writes -> ~41 us floor at the fill-demonstrated
// 6.6 TB/s. Harness dur_us includes a ~164 us 1 GiB poison fill.
//
// R5/R6/R7 post-mortem: three structurally different wave schedules
// (stall-and-go, double-buffer, 16-deep no-reuse pipeline) all ~254 us
// -> intra-wave pipelining is not the lever; kernel pinned at ~89 us
// (~3 TB/s), schedule-invariant.
//
// R8 theory: L2 write-allocate thrash. 256 MiB of output stores stream
// through the 4 MiB per-XCD L2s, continuously evicting the 256 KiB table;
// table reads keep missing to HBM -> up to ~256 MiB of HBM reads mixed
// into the write stream + r/w turnaround ~= the observed 2.2x gap. The
// poison fill is immune (pure writes, no read working set) -> 6.6 TB/s.
//
// R8 fix: NONTEMPORAL stores (global_store_dwordx4 ... nt, evict-first /
// no-allocate). Output stream stops displacing the table; table stays
// L2-resident; HBM traffic collapses to ~268 MB pure writes.
// Structure otherwise identical to R7 (16 rows/wave, distinct register
// per row, loads-then-stores, no WAR drain).

#define EMBED 256
#define CHUNKS_PER_ROW (EMBED / 4)      // 64 x 16B chunks per 1 KiB row
#define ROWS_PER_WAVE 16
#define WAVES_PER_BLOCK 4

typedef unsigned int u32x4 __attribute__((ext_vector_type(4)));

__global__ __launch_bounds__(256) void embedding_gather_kernel(
    const int* __restrict__ indices,          // [TOKENS] int32
    const u32x4* __restrict__ table,          // [VOCAB*EMBED] f32 as 16B chunks
    u32x4* __restrict__ out,                  // [TOKENS*EMBED] f32 as 16B chunks
    int tokens)
{
    const int lane    = threadIdx.x & 63;
    const int wave_id = blockIdx.x * WAVES_PER_BLOCK + (threadIdx.x >> 6);
    const long row_base = (long)wave_id * ROWS_PER_WAVE;
    if (row_base >= tokens) return;

    // One coalesced load: lane l (l < 16) holds the index for row row_base+l.
    int my_idx = 0;
    if (lane < ROWS_PER_WAVE && row_base + lane < tokens)
        my_idx = indices[row_base + lane];

    const u32x4* __restrict__ tb  = table + lane;                        // + lane*16B
    u32x4* __restrict__       dst = out + (size_t)row_base * CHUNKS_PER_ROW + lane;

    const long rem  = tokens - row_base;
    const int  rows = rem < ROWS_PER_WAVE ? (int)rem : ROWS_PER_WAVE;

    if (rows == ROWS_PER_WAVE) {
        // Distinct registers per row: no WAR hazard, no vmcnt(0) drain.
        u32x4 buf[ROWS_PER_WAVE];

        #pragma unroll
        for (int g = 0; g < ROWS_PER_WAVE; ++g) {
            const int idx = __builtin_amdgcn_readlane(my_idx, g);   // SGPR base
            buf[g] = tb[(size_t)idx * CHUNKS_PER_ROW];
        }
        #pragma unroll
        for (int g = 0; g < ROWS_PER_WAVE; ++g)
            __builtin_nontemporal_store(buf[g], &dst[(size_t)g * CHUNKS_PER_ROW]);
    } else {
        // Partial tail wave (not hit at 262144 tokens, kept for safety).
        for (int i = 0; i < rows; ++i) {
            const int idx = __builtin_amdgcn_readlane(my_idx, i);
            __builtin_nontemporal_store(tb[(size_t)idx * CHUNKS_PER_ROW],
                                        &dst[(size_t)i * CHUNKS_PER_ROW]);
        }
    }
}

extern "C" void kernel_launch(void* const* d_in, const int* in_sizes, int n_in,
                              void* d_out, int out_size, void* d_ws, size_t ws_size,
                              hipStream_t stream) {
    const int*   indices = (const int*)d_in[0];    // [262144] int32
    const u32x4* table   = (const u32x4*)d_in[1];  // [256*256] f32 as 16B chunks
    u32x4*       out     = (u32x4*)d_out;          // [262144*256] f32 as 16B chunks

    const int tokens = in_sizes[0];                                       // 262144
    const int waves  = (tokens + ROWS_PER_WAVE - 1) / ROWS_PER_WAVE;      // 16384
    const int blocks = (waves + WAVES_PER_BLOCK - 1) / WAVES_PER_BLOCK;   // 4096

    embedding_gather_kernel<<<blocks, 256, 0, stream>>>(indices, table, out, tokens);
}

// Round 4
// 255.402 us; speedup vs baseline: 1.0432x; 1.0432x over previous
//
#include <hip/hip_runtime.h>

// Embedding gather: out[token, :] = kernel[idx[token], :]  (all f32)
// TOKENS = 262144, EMBED = 256 (1 KiB/row), VOCAB = 256 (table 256 KiB).
// Output = 256 MiB HBM writes -> ~41 us floor at the fill-demonstrated
// 6.6 TB/s. Harness dur_us includes a ~164 us 1 GiB poison fill:
// kernel-only ~= dur_us - 164 (R4 comment 118us vs R5 harness 255.4us
// only reconciles this way). Kernel pinned at ~90 us across R5/R6/R7.
//
// R8 post-mortem: nt stores -12 us WORSE; L2-thrash theory also fails
// quantitatively (table re-touch 0.7us << L2 turnover 11us -> table stays
// hot under any replacement). Reverted.
//
// R9 theory: concurrency geometry. The 6.6 TB/s fill runs ~10% occupancy
// (~800 waves chip-wide, long sequential streams). R5-R7 ran 16-24
// waves/CU = ~6K concurrent 16 KiB write streams = ~24 streams interleaved
// per HBM pseudo-channel -> DRAM row-buffer thrash, ~2x write-rate loss,
// invariant under intra-wave scheduling (which is why 3 schedules tied).
// Fix: clone the fill's geometry. 256 blocks x 4 waves = 1024 persistent
// waves (1 block/CU), each owning 256 CONSECUTIVE rows (256 KiB stream,
// ~4 streams/channel). Windowed register pipeline (2 x 16 rows, distinct
// regs per window, next-window loads issued before current-window stores):
// WAR wait per window is vmcnt(15) (one store-ack, ~31 ops outstanding),
// never a drain. Indices preloaded in 4 coalesced loads.

#define EMBED 256
#define CHUNKS 64                       // 16B chunks per 1 KiB row
#define ROWS_PER_WAVE 256
#define W 16                            // window size (rows)
#define NW (ROWS_PER_WAVE / W)          // 16 windows
#define WAVES_PER_BLOCK 4

typedef unsigned int u32x4 __attribute__((ext_vector_type(4)));

#define LOADW(BUF, WIN)                                                       \
    _Pragma("unroll")                                                         \
    for (int g = 0; g < W; ++g) {                                             \
        const int r   = (WIN) * W + g;            /* compile-time */          \
        const int idx = __builtin_amdgcn_readlane(idxv[r >> 6], r & 63);      \
        BUF[g] = tb[(size_t)idx * CHUNKS];                                    \
    }

#define STOREW(BUF, WIN)                                                      \
    _Pragma("unroll")                                                         \
    for (int g = 0; g < W; ++g)                                               \
        dst[(size_t)((WIN) * W + g) * CHUNKS] = BUF[g];

__global__ __launch_bounds__(256) void embedding_gather_kernel(
    const int* __restrict__ indices,          // [TOKENS] int32
    const u32x4* __restrict__ table,          // [VOCAB*EMBED] f32 as 16B chunks
    u32x4* __restrict__ out,                  // [TOKENS*EMBED] f32 as 16B chunks
    int tokens)
{
    const int lane    = threadIdx.x & 63;
    const int wave_id = blockIdx.x * WAVES_PER_BLOCK + (threadIdx.x >> 6);
    const long row_base = (long)wave_id * ROWS_PER_WAVE;
    if (row_base >= tokens) return;

    // Preload all 256 indices for this wave: idxv[k] = indices[base + k*64 + lane].
    int idxv[4];
    #pragma unroll
    for (int k = 0; k < 4; ++k) {
        const long r = row_base + (long)k * 64 + lane;
        idxv[k] = (r < tokens) ? indices[r] : 0;
    }

    const u32x4* __restrict__ tb  = table + lane;                       // + lane*16B
    u32x4* __restrict__       dst = out + (size_t)row_base * CHUNKS + lane;

    if (row_base + ROWS_PER_WAVE <= tokens) {
        // Full wave: 16 windows of 16 rows, two register windows, pipelined.
        u32x4 bufA[W], bufB[W];

        LOADW(bufA, 0)
        #pragma unroll
        for (int w = 0; w < NW; w += 2) {
            LOADW(bufB, w + 1)              // w+1 < NW always (NW even)
            STOREW(bufA, w)
            if (w + 2 < NW) { LOADW(bufA, w + 2) }
            STOREW(bufB, w + 1)
        }
    } else {
        // Partial tail wave (not hit at 262144 tokens, kept for safety).
        const long rem  = tokens - row_base;
        const int  rows = (int)rem;
        for (int i = 0; i < rows; ++i) {
            const int idx = __builtin_amdgcn_readlane(idxv[i >> 6], i & 63);
            dst[(size_t)i * CHUNKS] = tb[(size_t)idx * CHUNKS];
        }
    }
}

extern "C" void kernel_launch(void* const* d_in, const int* in_sizes, int n_in,
                              void* d_out, int out_size, void* d_ws, size_t ws_size,
                              hipStream_t stream) {
    const int*   indices = (const int*)d_in[0];    // [262144] int32
    const u32x4* table   = (const u32x4*)d_in[1];  // [256*256] f32 as 16B chunks
    u32x4*       out     = (u32x4*)d_out;          // [262144*256] f32 as 16B chunks

    const int tokens = in_sizes[0];                                        // 262144
    const int waves  = (tokens + ROWS_PER_WAVE - 1) / ROWS_PER_WAVE;       // 1024
    const int blocks = (waves + WAVES_PER_BLOCK - 1) / WAVES_PER_BLOCK;    // 256

    embedding_gather_kernel<<<blocks, 256, 0, stream>>>(indices, table, out, tokens);
}